// Round 8
// baseline (89.604 us; speedup 1.0000x reference)
//
#include <hip/hip_runtime.h>
#include <math.h>

#define BB 16
#define TD 1024
#define HD 512
#define UD 600
#define AD 80
#define KG 10
#define PC 30      // 3*K
#define PP 32      // padded param cols

#define LOG2E 1.4426950408889634f

#if __has_builtin(__builtin_amdgcn_exp2f)
#define EXP2F(x) __builtin_amdgcn_exp2f(x)
#else
#define EXP2F(x) exp2f(x)
#endif

typedef short v8s __attribute__((ext_vector_type(8)));
typedef float v4f __attribute__((ext_vector_type(4)));

__device__ inline unsigned short f2bf(float f) {            // RNE fp32->bf16
    unsigned u = __float_as_uint(f);
    return (unsigned short)((u + 0x7FFF + ((u >> 16) & 1)) >> 16);
}

// ======== kernel 0: pack W into MFMA B-fragment order, split bf16 hi/lo ====
// mfma_f32_16x16x32_bf16 B-layout: B[k = (lane>>4)*8 + j][n = lane&15].
// Wf[((kt*2+n)*64 + lane)*8 + j] covers k = kt*32 + (lane>>4)*8 + j,
// c = n*16 + (lane&15)  (c>=30 zero-padded). 32768 entries each for hi/lo.
__global__ void k_wprep(const float* __restrict__ W,
                        unsigned short* __restrict__ Wfh,
                        unsigned short* __restrict__ Wfl) {
    int p = blockIdx.x * 256 + threadIdx.x;
    for (; p < 32768; p += 256 * 32) {
        int j = p & 7, l = (p >> 3) & 63, n = (p >> 9) & 1, kt = p >> 10;
        int k = kt * 32 + ((l >> 4) * 8) + j;
        int c = n * 16 + (l & 15);
        float v = (c < PC) ? W[k * PC + c] : 0.f;
        unsigned short h = f2bf(v);
        float hi_f = __uint_as_float(((unsigned)h) << 16);
        Wfh[p] = h;
        Wfl[p] = f2bf(v - hi_f);
    }
}

// ======== fused kernel: params GEMM (MFMA split-bf16) + exp + gaussian =====
// 1024 blocks x 320 thr (5 waves); block = (batch b, 16 t's). TT=16 (vs 32)
// doubles blocks/CU to 4 (20 waves/CU) -- R1..R7 post-mortems all point at
// latency exposure, not throughput, as the gap vs the ~6us work model.
// Phase A: waves 0-3 = k-slices of 128 (4 ktiles), 2 Ntiles, 3 MFMA passes
//   (hh, lh, hl) ~ fp32 accuracy. Wave 4 concurrently prefetches cs chunk 0
//   (speculative: ch_lo==0 for real data; any other chunk stages normally).
// Phase B: reduce 4 partials + exp -> params_l (no global round-trip).
// Phase C: dynamic u-range (skip chunks where every term < 2^-46*max(a,1);
//   abs err < 1e-9 for ANY input, graceful full-loop fallback) + einsum.
#define TT 16     // t-tile per block
#define UC 40     // u chunk
#define NCHUNK 15 // 600/40
#define NTHR 320  // 5 waves

__global__ __launch_bounds__(NTHR, 4) void k_fused(const float* __restrict__ x,
                                                   const unsigned short* __restrict__ Wfh,
                                                   const unsigned short* __restrict__ Wfl,
                                                   const float* __restrict__ bias,
                                                   const float* __restrict__ cs,
                                                   float* __restrict__ out) {
    __shared__ float red[4 * TT * 33];    // [wv][row16][col33] 8448 B
    __shared__ float params_l[TT * 36];   // pitch 36
    __shared__ float cs_l[UC * AD];       // [u][a] pitch 80, 12.8 KB
    __shared__ float phi2[TT * 44];       // [t][u] pitch 44
    __shared__ float range_l[2];

    int tid = threadIdx.x;
    int b = blockIdx.y;
    int t0 = blockIdx.x * TT;
    long r0 = (long)b * TD + t0;          // first global row of this tile

    int wv = tid >> 6;                    // 0..4
    int l = tid & 63;
    int quad = l >> 4, m = l & 15;

    const float* csb = cs + (long)b * UD * AD;

    // ================= Phase A: params GEMM (waves 0-3) =================
    if (wv < 4) {
        v4f acc[2] = {{0.f, 0.f, 0.f, 0.f}, {0.f, 0.f, 0.f, 0.f}};

        #pragma unroll
        for (int kt = 0; kt < 4; kt++) {
            int g = wv * 4 + kt;          // global ktile 0..15
            const float* xr = x + (r0 + m) * HD + g * 32 + quad * 8;
            float4 xa = *(const float4*)(xr);
            float4 xb = *(const float4*)(xr + 4);
            float xf[8] = {xa.x, xa.y, xa.z, xa.w, xb.x, xb.y, xb.z, xb.w};
            v8s ah, al;
            #pragma unroll
            for (int j = 0; j < 8; j++) {
                unsigned short h = f2bf(xf[j]);
                ah[j] = (short)h;
                al[j] = (short)f2bf(xf[j] - __uint_as_float(((unsigned)h) << 16));
            }
            #pragma unroll
            for (int n = 0; n < 2; n++) {
                uint4 uh = *(const uint4*)&Wfh[((g * 2 + n) * 64 + l) * 8];
                uint4 ul = *(const uint4*)&Wfl[((g * 2 + n) * 64 + l) * 8];
                v8s bh, bl;
                __builtin_memcpy(&bh, &uh, 16);
                __builtin_memcpy(&bl, &ul, 16);
                acc[n] = __builtin_amdgcn_mfma_f32_16x16x32_bf16(ah, bh, acc[n], 0, 0, 0);
                acc[n] = __builtin_amdgcn_mfma_f32_16x16x32_bf16(al, bh, acc[n], 0, 0, 0);
                acc[n] = __builtin_amdgcn_mfma_f32_16x16x32_bf16(ah, bl, acc[n], 0, 0, 0);
            }
        }

        // C/D layout: row = quad*4 + reg, col = lane&15 (+ n*16)
        #pragma unroll
        for (int n = 0; n < 2; n++)
            #pragma unroll
            for (int r = 0; r < 4; r++)
                red[wv * (TT * 33) + (quad * 4 + r) * 33 + n * 16 + m] = acc[n][r];
    } else {
        // ---- wave 4: speculative prefetch of cs chunk 0 (800 float4)
        for (int idx = l; idx < (UC * AD) / 4; idx += 64)
            *(float4*)&cs_l[idx * 4] = *(const float4*)&csb[idx * 4];
    }
    __syncthreads();

    // ================= Phase B: reduce + exp transform ==================
    // params_l[t][c]: c 0..9 a=exp(p); 10..19 nb=-exp(p)*log2e; 20..29 k=exp(p)
    for (int idx = tid; idx < TT * PC; idx += NTHR) {
        int r = idx / PC, c = idx - r * PC;
        float s = red[0 * (TT * 33) + r * 33 + c] + red[1 * (TT * 33) + r * 33 + c]
                + red[2 * (TT * 33) + r * 33 + c] + red[3 * (TT * 33) + r * 33 + c];
        float e = __expf(s + bias[c]);
        params_l[r * 36 + c] = (c >= 10 && c < 20) ? (-e * LOG2E) : e;
    }
    __syncthreads();

    // ================= Phase C: gaussian window + einsum ================
    int tt = tid & 15;                    // param row for phi role
    int sub = tid >> 4;                   // 0..19 -> u = sub*2, sub*2+1
    float pa[KG], pnb[KG], pk[KG];
    #pragma unroll
    for (int q = 0; q < KG; q++) {
        pa[q]  = params_l[tt * 36 + q];
        pnb[q] = params_l[tt * 36 + 10 + q];
        pk[q]  = params_l[tt * 36 + 20 + q];
    }

    // dynamic contributing u-range; wave 0 reduces (its 64 lanes cover all t)
    {
        float lo = 1e30f, hi = -1e30f;
        #pragma unroll
        for (int q = 0; q < KG; q++) {
            float bits = 46.f + fmaxf(0.f, __log2f(pa[q]));
            float w = __fsqrt_rn(bits / (-pnb[q]));   // pnb<0 strictly
            lo = fminf(lo, pk[q] - w);
            hi = fmaxf(hi, pk[q] + w);
        }
        if (tid < 64) {
            #pragma unroll
            for (int mk = 1; mk < 64; mk <<= 1) {
                lo = fminf(lo, __shfl_xor(lo, mk));
                hi = fmaxf(hi, __shfl_xor(hi, mk));
            }
            if (tid == 0) { range_l[0] = lo; range_l[1] = hi; }
        }
    }
    __syncthreads();
    float lo_m = fminf(fmaxf(range_l[0], 0.f), (float)(UD - 1));
    float hi_m = fminf(fmaxf(range_l[1], 0.f), (float)(UD - 1));
    int ch_lo = (int)lo_m / UC;
    int ch_hi = (int)hi_m / UC;
    if (ch_lo > ch_hi) ch_lo = ch_hi;

    // einsum role: thread owns t = ty, a-quad tx*4
    int tx = tid % 20;   // 0..19
    int ty = tid / 20;   // 0..15
    float4 acc0 = {0.f, 0.f, 0.f, 0.f};

    for (int ch = ch_lo; ch <= ch_hi; ch++) {
        int u0 = ch * UC;
        __syncthreads();   // protect cs_l/phi2 from previous chunk's readers

        // stage char_seq chunk (chunk 0 was prefetched by wave 4 in Phase A)
        if (ch != 0) {
            for (int idx = tid; idx < (UC * AD) / 4; idx += NTHR) {
                *(float4*)&cs_l[idx * 4] = *(const float4*)&csb[u0 * AD + idx * 4];
            }
        }

        // compute phi for my t, my 2 u's
        float ph[2];
        #pragma unroll
        for (int i = 0; i < 2; i++) {
            float uf = (float)(u0 + sub * 2 + i);
            float ss = 0.f;
            #pragma unroll
            for (int q = 0; q < KG; q++) {
                float d = uf - pk[q];
                ss += pa[q] * EXP2F(pnb[q] * d * d);
            }
            ph[i] = ss;
        }
        *(float2*)&phi2[tt * 44 + sub * 2] = make_float2(ph[0], ph[1]);
        __syncthreads();

        // einsum: out[t][a] += phi[t][u] * cs[u][a]; b128 phi + b128 cs
        #pragma unroll 2
        for (int g = 0; g < 10; g++) {
            float4 p0 = *(const float4*)&phi2[ty * 44 + g * 4];
            #pragma unroll
            for (int i = 0; i < 4; i++) {
                float4 c4 = *(const float4*)&cs_l[(g * 4 + i) * AD + tx * 4];
                float pi0 = (i == 0) ? p0.x : (i == 1) ? p0.y : (i == 2) ? p0.z : p0.w;
                acc0.x += pi0 * c4.x; acc0.y += pi0 * c4.y;
                acc0.z += pi0 * c4.z; acc0.w += pi0 * c4.w;
            }
        }
    }

    // store 1 t-row x 4 a's
    *(float4*)(out + (r0 + ty) * AD + tx * 4) = acc0;
}

extern "C" void kernel_launch(void* const* d_in, const int* in_sizes, int n_in,
                              void* d_out, int out_size, void* d_ws, size_t ws_size,
                              hipStream_t stream) {
    const float* lstm = (const float*)d_in[0];   // [16,1024,512]
    const float* cs   = (const float*)d_in[1];   // [16,600,80]
    const float* W    = (const float*)d_in[2];   // [512,30]
    const float* bias = (const float*)d_in[3];   // [30]
    float* out = (float*)d_out;                  // [16,1024,80]

    unsigned short* Wfh = (unsigned short*)d_ws;     // 64 KB
    unsigned short* Wfl = Wfh + 32768;               // 64 KB

    k_wprep<<<32, 256, 0, stream>>>(W, Wfh, Wfl);
    dim3 grid(TD / TT, BB);
    k_fused<<<grid, NTHR, 0, stream>>>(lstm, Wfh, Wfl, bias, cs, out);
}